// Round 11
// baseline (590.750 us; speedup 1.0000x reference)
//
#include <hip/hip_runtime.h>
#include <hip/hip_bf16.h>

#define TSEQ 1024
#define NB   128
#define HID  128
#define QDIM 16

typedef unsigned int  u32;
typedef unsigned short u16;
typedef float f32x2 __attribute__((ext_vector_type(2)));

// ---------------- cross-lane helpers (wave64) ----------------

template<int CTRL>
__device__ __forceinline__ int dpp_i(int x) {
  return __builtin_amdgcn_update_dpp(0, x, CTRL, 0xF, 0xF, true);
}
template<int CTRL>
__device__ __forceinline__ float dpp_f(float x) {
  return __int_as_float(dpp_i<CTRL>(__float_as_int(x)));
}

#ifdef __has_builtin
#if __has_builtin(__builtin_amdgcn_permlane16_swap) && __has_builtin(__builtin_amdgcn_permlane32_swap)
#define HAS_PLS 1
#endif
#endif
#ifndef HAS_PLS
#define HAS_PLS 0
#endif

__device__ __forceinline__ float pls16_sum(float x) {
#if HAS_PLS
  auto r = __builtin_amdgcn_permlane16_swap(__float_as_uint(x), __float_as_uint(x), false, false);
  return __uint_as_float(r[0]) + __uint_as_float(r[1]);
#else
  return x + __shfl_xor(x, 16, 64);
#endif
}
__device__ __forceinline__ float pls32_sum(float x) {
#if HAS_PLS
  auto r = __builtin_amdgcn_permlane32_swap(__float_as_uint(x), __float_as_uint(x), false, false);
  return __uint_as_float(r[0]) + __uint_as_float(r[1]);
#else
  return x + __shfl_xor(x, 32, 64);
#endif
}

__device__ __forceinline__ float rcpf(float x) { return __builtin_amdgcn_rcpf(x); }

__device__ __forceinline__ float ex2(float x) {
#if defined(__has_builtin)
#if __has_builtin(__builtin_amdgcn_exp2f)
  return __builtin_amdgcn_exp2f(x);
#else
  return exp2f(x);
#endif
#else
  return exp2f(x);
#endif
}

__device__ __forceinline__ u16 f2bf(float f) {
  u32 u = __float_as_uint(f);
  u32 r = (u + 0x7FFFu + ((u >> 16) & 1u)) >> 16;
  return (u16)r;
}

__device__ __forceinline__ f32x2 s2(float x) { f32x2 r; r.x = x; r.y = x; return r; }

// CNOT-ladder index map g (verified in R1-R10).
__device__ __forceinline__ int gperm(int t) {
  int u = t;
#define APPLY(c, tt) u ^= (((u >> (3 - (c))) & 1) << (3 - (tt)));
  APPLY(3, 1) APPLY(2, 0) APPLY(1, 3) APPLY(0, 2)
  APPLY(3, 0) APPLY(2, 3) APPLY(1, 2) APPLY(0, 1)
#undef APPLY
  return u;
}

// ---------------- kernel 1: xwP[b,t,j] = x[b,t,:] @ W_x[:,g(j)] + b_in[g(j)] ----------------

__global__ __launch_bounds__(256) void xw_kernel(
    const float* __restrict__ x, const float* __restrict__ W_in,
    const float* __restrict__ b_in, float* __restrict__ xw) {
  __shared__ __align__(16) float xs[16][132];
  __shared__ float wl[2048];
  __shared__ float bl[16];
  const int tid = threadIdx.x;
  const long r0 = (long)blockIdx.x * 16;
#pragma unroll
  for (int i = 0; i < 8; ++i) {
    int idx = tid + i * 256;
    xs[idx >> 7][idx & 127] = x[(r0 + (idx >> 7)) * 128 + (idx & 127)];
  }
#pragma unroll
  for (int i = 0; i < 8; ++i) {
    int idx = tid + i * 256;
    wl[idx] = W_in[2048 + idx];   // W_x = W_in[128:256, :]
  }
  if (tid < 16) bl[tid] = b_in[tid];
  __syncthreads();
  const int rr = tid >> 4, j = tid & 15;
  const int gj = gperm(j);
  float s = bl[gj];
#pragma unroll
  for (int k4 = 0; k4 < 32; ++k4) {
    float4 v = *reinterpret_cast<const float4*>(&xs[rr][k4 * 4]);
    int kb = k4 * 4;
    s = fmaf(v.x, wl[(kb + 0) * 16 + gj], s);
    s = fmaf(v.y, wl[(kb + 1) * 16 + gj], s);
    s = fmaf(v.z, wl[(kb + 2) * 16 + gj], s);
    s = fmaf(v.w, wl[(kb + 3) * 16 + gj], s);
  }
  xw[(r0 + rr) * 16 + j] = s;
}

// ---------------- kernel 2: recurrence. 256 blocks x 1 wave; all-register ----------------
// Chain-optimized (R11): L2E factors folded into gate tables (no nic/i2c muls
// on chain); tree dots (3 levels); blend via q = z+(1-z)h and s = -2z computed
// off-chain so the h2 tail is ex2->add->rcp->fma; lane owns adjacent columns
// k = m = 2*tid, 2*tid+1 so the output store is one dwordx2 (still coalesced).

template<bool BF16WS>
__global__ __launch_bounds__(64)
__attribute__((amdgpu_waves_per_eu(1, 2)))
void qbigru_main(
    const float* __restrict__ W_in,
    const float* __restrict__ W_out,
    const float* __restrict__ b_out,
    const float* __restrict__ thr_f, const float* __restrict__ thr1_f, const float* __restrict__ thu_f,
    const float* __restrict__ thr_b, const float* __restrict__ thr1_b, const float* __restrict__ thu_b,
    const float* __restrict__ xw,
    float* __restrict__ out,
    void* __restrict__ bwdws) {
  const int tid = threadIdx.x;
  const int l4  = tid & 15;
  const int dir = blockIdx.x >> 7;
  const int b   = blockIdx.x & 127;

  // xor4-within-row via row_shl:4 / row_shr:4 + probe-derived select (convention-proof).
  const int pshl = dpp_i<0x104>(tid);
  const int sel4 = (pshl == (tid ^ 4)) ? ~0 : 0;
  auto xor4f = [&](float x) {
    int a = dpp_i<0x104>(__float_as_int(x));
    int c = dpp_i<0x114>(__float_as_int(x));
    return __int_as_float((a & sel4) | (c & ~sel4));
  };

  // Select-free reduce-scatter. Input: v[i] = partial of column (i ^ l4).
  // Output: full 64-lane sum for column l4, replicated in every lane.
  auto bfr = [&](const float* v) -> float {
    float w1[8];
#pragma unroll
    for (int j = 0; j < 8; ++j) w1[j] = v[2 * j] + dpp_f<0xB1>(v[2 * j + 1]);   // col bit0 (xor1)
    float w2[4];
#pragma unroll
    for (int j = 0; j < 4; ++j) w2[j] = w1[2 * j] + dpp_f<0x4E>(w1[2 * j + 1]); // col bit1 (xor2)
    float w3[2];
#pragma unroll
    for (int j = 0; j < 2; ++j) w3[j] = w2[j] + dpp_f<0x128>(w2[j + 2]);        // col bit3 (xor8)
    float y0 = w3[0] + xor4f(w3[1]);                                            // col bit2 (xor4)
    return pls32_sum(pls16_sum(y0));
  };

  // +/- butterfly: eb[B](l) = (-1)^{l_B} * sum_s p[s]*(1-2*bit_B(s)); n2 = sum p.
  auto ebf = [&](float p, float& n2, float* eb) {
    float s4 = xor4f(p);
    float P  = p + s4, M2 = p - s4;
    float dP = dpp_f<0x128>(P), dM2 = dpp_f<0x128>(M2);
    float P3 = P + dP, M3 = P - dP; M2 = M2 + dM2;
    float a1 = dpp_f<0x4E>(P3), a2 = dpp_f<0x4E>(M3), a3 = dpp_f<0x4E>(M2);
    float P1 = P3 + a1, M1 = P3 - a1; M3 += a2; M2 += a3;
    float b0_ = dpp_f<0xB1>(P1), b1_ = dpp_f<0xB1>(M1), b3_ = dpp_f<0xB1>(M3), b2_ = dpp_f<0xB1>(M2);
    n2 = P1 + b0_;
    eb[0] = P1 - b0_; eb[1] = M1 + b1_; eb[3] = M3 + b3_; eb[2] = M2 + b2_;
  };

  // ---- per-lane constants ----
  const float* thr  = dir ? thr_b  : thr_f;
  const float* thr1 = dir ? thr1_b : thr1_f;
  const float* thu  = dir ? thu_b  : thu_f;

  const int k0 = 2 * tid, k1 = 2 * tid + 1;   // this lane's hidden units (k == m)

  // W_h, XOR layout + CNOT perm folded: slot i holds column g(i ^ l4).
  f32x2 w0p[8], w1p[8];
#pragma unroll
  for (int i = 0; i < 8; ++i) {
    int ja = gperm((2 * i) ^ l4), jb = gperm((2 * i + 1) ^ l4);
    f32x2 a, c;
    a.x = W_in[k0 * QDIM + ja];  a.y = W_in[k0 * QDIM + jb];
    c.x = W_in[k1 * QDIM + ja];  c.y = W_in[k1 * QDIM + jb];
    w0p[i] = a; w1p[i] = c;
  }

  // W_out pk pairs over (m = k0, k1), wire w = 3-B, with e-butterfly sign
  // (-1)^{l_B}, the analytic cos(theta_w) factor, AND the log2(e) gate-scale
  // folded in (woR/woZ: -L2E for sigmoid; woH: +2*L2E for tanh).
  const float L2E = 1.4426950408889634f;
  f32x2 woRpk[4], woZpk[4], woHpk[4];
#pragma unroll
  for (int B = 0; B < 4; ++B) {
    float sgn = ((tid >> B) & 1) ? -1.f : 1.f;
    float cR = cosf(thr[3 - B])  * sgn * (-L2E);
    float cZ = cosf(thu[3 - B])  * sgn * (-L2E);
    float cH = cosf(thr1[3 - B]) * sgn * (2.f * L2E);
    float wo0 = W_out[(3 - B) * HID + k0];
    float wo1 = W_out[(3 - B) * HID + k1];
    f32x2 rr_, zz_, hh_;
    rr_.x = wo0 * cR;  rr_.y = wo1 * cR;
    zz_.x = wo0 * cZ;  zz_.y = wo1 * cZ;
    hh_.x = wo0 * cH;  hh_.y = wo1 * cH;
    woRpk[B] = rr_; woZpk[B] = zz_; woHpk[B] = hh_;
  }
  f32x2 nbcpk, bc2pk;
  nbcpk.x = -b_out[k0] * L2E;         nbcpk.y = -b_out[k1] * L2E;
  bc2pk.x =  b_out[k0] * (2.f * L2E); bc2pk.y =  b_out[k1] * (2.f * L2E);

  // tree dot: 3 dependency levels
  auto dot4pk = [](const float* e, const f32x2* w) -> f32x2 {
    f32x2 d01 = s2(e[1]) * w[1] + s2(e[0]) * w[0];
    f32x2 d23 = s2(e[3]) * w[3] + s2(e[2]) * w[2];
    return d01 + d23;
  };

  f32x2 hpk; hpk.x = 0.f; hpk.y = 0.f;   // h[k0], h[k1]
  const float* pxw = xw + ((long)b * TSEQ + (dir ? TSEQ - 1 : 0)) * QDIM;
  const long xstep = dir ? -QDIM : QDIM;
  float xc = pxw[l4]; pxw += xstep;
  float xn = pxw[l4]; pxw += xstep;

  float* po  = out + (long)b * TSEQ * HID + k0;
  float* pbf = (float*)bwdws + (long)b * TSEQ * HID + k0;
  u32*   pbh = (u32*)bwdws + ((long)b * TSEQ * HID >> 1) + tid;

#pragma unroll 1
  for (int t = 0; t < TSEQ; ++t) {
    float xnn = pxw[l4]; pxw += xstep;   // prefetch t+2 (ws padded; overrun harmless)

    // ---- y = h @ W_h (permuted cols) + xwP ----
    f32x2 hh0 = s2(hpk.x);
    f32x2 hh1 = s2(hpk.y);
    float v[16];
#pragma unroll
    for (int i = 0; i < 8; ++i) {
      f32x2 a = hh0 * w0p[i] + hh1 * w1p[i];
      v[2 * i] = a.x; v[2 * i + 1] = a.y;
    }
    float yv = bfr(v) + xc;

    // ---- VQC1 collapsed: p[col] = yP[col]^2 ----
    float prb = yv * yv;

    float n2, eb[4];
    ebf(prb, n2, eb);
    float inv = rcpf(n2);   // n2 == |y|^2, shared by both gate types

    // gate dots (tables carry cos(theta), sign, and L2E scale)
    f32x2 rd = dot4pk(eb, woRpk);
    f32x2 zd = dot4pk(eb, woZpk);

    f32x2 ra = rd * s2(inv) + nbcpk;
    f32x2 za = zd * s2(inv) + nbcpk;
    float r0 = rcpf(1.f + ex2(ra.x));
    float r1 = rcpf(1.f + ex2(ra.y));
    float z0 = rcpf(1.f + ex2(za.x));
    float z1 = rcpf(1.f + ex2(za.y));

    // off-chain blend prep: q = z + (1-z)h ; s = -2z (ready during matvec2)
    f32x2 zpk;  zpk.x = z0; zpk.y = z1;
    f32x2 omz = s2(1.f) - zpk;
    f32x2 qpk = omz * hpk + zpk;
    f32x2 spk = s2(-2.f) * zpk;

    // ---- v1 = (r*h) @ W_h + xwP ----
    f32x2 rpk; rpk.x = r0; rpk.y = r1;
    f32x2 rh = rpk * hpk;
    hh0 = s2(rh.x);
    hh1 = s2(rh.y);
#pragma unroll
    for (int i = 0; i < 8; ++i) {
      f32x2 a = hh0 * w0p[i] + hh1 * w1p[i];
      v[2 * i] = a.x; v[2 * i + 1] = a.y;
    }
    float vv = bfr(v) + xc;

    // ---- VQC2 collapsed ----
    float prb2 = vv * vv;

    float n2b, eb2[4];
    ebf(prb2, n2b, eb2);
    float invb = rcpf(n2b);
    f32x2 hd = dot4pk(eb2, woHpk);
    f32x2 ha = hd * s2(invb) + bc2pk;
    // w = 1/(1+e^{2a}); h2 = 1-2w; hn = z*h2+(1-z)h = s*w + q
    float wq0 = rcpf(1.f + ex2(ha.x));
    float wq1 = rcpf(1.f + ex2(ha.y));
    f32x2 wpk; wpk.x = wq0; wpk.y = wq1;
    hpk = spk * wpk + qpk;

    f32x2 opk = hpk * s2(0.5f);
    if (dir == 0) {
      *reinterpret_cast<f32x2*>(po) = opk;
      po += HID;
    } else if (BF16WS) {
      *pbh = (u32)f2bf(opk.x) | ((u32)f2bf(opk.y) << 16);
      pbh += HID / 2;
    } else {
      *reinterpret_cast<f32x2*>(pbf) = opk;
      pbf += HID;
    }

    xc = xn; xn = xnn;
  }
}

// ---------------- kernel 3: out += bwd trajectory ----------------

template<bool BF16WS>
__global__ __launch_bounds__(256) void combine_k(float* __restrict__ out,
                                                 const void* __restrict__ bwd, long n4) {
  long i = (long)blockIdx.x * 256 + threadIdx.x;
  const long stride = (long)gridDim.x * 256;
  for (; i < n4; i += stride) {
    float4 o = reinterpret_cast<float4*>(out)[i];
    float ax, ay, az, aw;
    if (BF16WS) {
      ushort4 u = reinterpret_cast<const ushort4*>(bwd)[i];
      ax = __uint_as_float((u32)u.x << 16);
      ay = __uint_as_float((u32)u.y << 16);
      az = __uint_as_float((u32)u.z << 16);
      aw = __uint_as_float((u32)u.w << 16);
    } else {
      float4 a = reinterpret_cast<const float4*>(bwd)[i];
      ax = a.x; ay = a.y; az = a.z; aw = a.w;
    }
    o.x += ax; o.y += ay; o.z += az; o.w += aw;
    reinterpret_cast<float4*>(out)[i] = o;
  }
}

// ---------------- launch ----------------

extern "C" void kernel_launch(void* const* d_in, const int* in_sizes, int n_in,
                              void* d_out, int out_size, void* d_ws, size_t ws_size,
                              hipStream_t stream) {
  const float* x     = (const float*)d_in[0];
  const float* W_in  = (const float*)d_in[1];
  const float* b_in  = (const float*)d_in[2];
  const float* W_out = (const float*)d_in[3];
  const float* b_out = (const float*)d_in[4];
  const float* thr_f  = (const float*)d_in[5];
  const float* thr1_f = (const float*)d_in[6];
  const float* thu_f  = (const float*)d_in[7];
  const float* thr_b  = (const float*)d_in[8];
  const float* thr1_b = (const float*)d_in[9];
  const float* thu_b  = (const float*)d_in[10];
  float* out = (float*)d_out;

  char* ws = (char*)d_ws;
  const size_t PAD = 4096;   // xw prefetch over/under-run guard
  const size_t xw_bytes = (size_t)NB * TSEQ * QDIM * sizeof(float);   // 8 MB
  float* xw = (float*)(ws + PAD);
  void* bwd = (void*)(ws + PAD + xw_bytes + PAD);
  const size_t need_f32 = 2 * PAD + xw_bytes + (size_t)NB * TSEQ * HID * sizeof(float);
  const bool f32ws = (ws_size >= need_f32);

  xw_kernel<<<(NB * TSEQ) / 16, 256, 0, stream>>>(x, W_in, b_in, xw);

  if (f32ws) {
    qbigru_main<false><<<256, 64, 0, stream>>>(W_in, W_out, b_out,
        thr_f, thr1_f, thu_f, thr_b, thr1_b, thu_b, xw, out, bwd);
  } else {
    qbigru_main<true><<<256, 64, 0, stream>>>(W_in, W_out, b_out,
        thr_f, thr1_f, thu_f, thr_b, thr1_b, thu_b, xw, out, bwd);
  }

  const long n4 = (long)NB * TSEQ * HID / 4;
  if (f32ws) combine_k<false><<<2048, 256, 0, stream>>>(out, bwd, n4);
  else       combine_k<true><<<2048, 256, 0, stream>>>(out, bwd, n4);
}

// Round 12
// 480.078 us; speedup vs baseline: 1.2305x; 1.2305x over previous
//
#include <hip/hip_runtime.h>
#include <hip/hip_bf16.h>
#include <type_traits>

#define TSEQ 1024
#define NB   128
#define HID  128
#define QDIM 16

typedef unsigned int  u32;
typedef unsigned short u16;
typedef float f32x2 __attribute__((ext_vector_type(2)));

// ---------------- cross-lane helpers (wave64) ----------------

template<int CTRL>
__device__ __forceinline__ int dpp_i(int x) {
  return __builtin_amdgcn_update_dpp(0, x, CTRL, 0xF, 0xF, true);
}
template<int CTRL>
__device__ __forceinline__ float dpp_f(float x) {
  return __int_as_float(dpp_i<CTRL>(__float_as_int(x)));
}

#ifdef __has_builtin
#if __has_builtin(__builtin_amdgcn_permlane16_swap) && __has_builtin(__builtin_amdgcn_permlane32_swap)
#define HAS_PLS 1
#endif
#endif
#ifndef HAS_PLS
#define HAS_PLS 0
#endif

__device__ __forceinline__ float pls16_sum(float x) {
#if HAS_PLS
  auto r = __builtin_amdgcn_permlane16_swap(__float_as_uint(x), __float_as_uint(x), false, false);
  return __uint_as_float(r[0]) + __uint_as_float(r[1]);
#else
  return x + __shfl_xor(x, 16, 64);
#endif
}
__device__ __forceinline__ float pls32_sum(float x) {
#if HAS_PLS
  auto r = __builtin_amdgcn_permlane32_swap(__float_as_uint(x), __float_as_uint(x), false, false);
  return __uint_as_float(r[0]) + __uint_as_float(r[1]);
#else
  return x + __shfl_xor(x, 32, 64);
#endif
}

__device__ __forceinline__ float rcpf(float x) { return __builtin_amdgcn_rcpf(x); }

__device__ __forceinline__ float ex2(float x) {
#if defined(__has_builtin)
#if __has_builtin(__builtin_amdgcn_exp2f)
  return __builtin_amdgcn_exp2f(x);
#else
  return exp2f(x);
#endif
#else
  return exp2f(x);
#endif
}

__device__ __forceinline__ u16 f2bf(float f) {
  u32 u = __float_as_uint(f);
  u32 r = (u + 0x7FFFu + ((u >> 16) & 1u)) >> 16;
  return (u16)r;
}

__device__ __forceinline__ f32x2 s2(float x) { f32x2 r; r.x = x; r.y = x; return r; }

// CNOT-ladder index map g (verified in R1-R11).
__device__ __forceinline__ int gperm(int t) {
  int u = t;
#define APPLY(c, tt) u ^= (((u >> (3 - (c))) & 1) << (3 - (tt)));
  APPLY(3, 1) APPLY(2, 0) APPLY(1, 3) APPLY(0, 2)
  APPLY(3, 0) APPLY(2, 3) APPLY(1, 2) APPLY(0, 1)
#undef APPLY
  return u;
}

// ---------------- kernel 1: xwP[b,t,j] = x[b,t,:] @ W_x[:,g(j)] + b_in[g(j)] ----------------

__global__ __launch_bounds__(256) void xw_kernel(
    const float* __restrict__ x, const float* __restrict__ W_in,
    const float* __restrict__ b_in, float* __restrict__ xw) {
  __shared__ __align__(16) float xs[16][132];
  __shared__ float wl[2048];
  __shared__ float bl[16];
  const int tid = threadIdx.x;
  const long r0 = (long)blockIdx.x * 16;
#pragma unroll
  for (int i = 0; i < 8; ++i) {
    int idx = tid + i * 256;
    xs[idx >> 7][idx & 127] = x[(r0 + (idx >> 7)) * 128 + (idx & 127)];
  }
#pragma unroll
  for (int i = 0; i < 8; ++i) {
    int idx = tid + i * 256;
    wl[idx] = W_in[2048 + idx];   // W_x = W_in[128:256, :]
  }
  if (tid < 16) bl[tid] = b_in[tid];
  __syncthreads();
  const int rr = tid >> 4, j = tid & 15;
  const int gj = gperm(j);
  float s = bl[gj];
#pragma unroll
  for (int k4 = 0; k4 < 32; ++k4) {
    float4 v = *reinterpret_cast<const float4*>(&xs[rr][k4 * 4]);
    int kb = k4 * 4;
    s = fmaf(v.x, wl[(kb + 0) * 16 + gj], s);
    s = fmaf(v.y, wl[(kb + 1) * 16 + gj], s);
    s = fmaf(v.z, wl[(kb + 2) * 16 + gj], s);
    s = fmaf(v.w, wl[(kb + 3) * 16 + gj], s);
  }
  xw[(r0 + rr) * 16 + j] = s;
}

// ---------------- kernel 2: recurrence. 256 blocks x 1 wave; all-register ----------------
// R12: matvec partials in ROTATION layout (slot i of lane l holds column
// (l+i)&15) so every reduce level is a plain add with native row_ror DPP
// source (fusable, no xor4 emulation). Rotation direction resolved by a
// lane-id probe selecting one of two template instantiations of the loop.
// bwd trajectory stored bf16 (combine reads half the bytes).

__global__ __launch_bounds__(64)
__attribute__((amdgpu_waves_per_eu(1, 2)))
void qbigru_main(
    const float* __restrict__ W_in,
    const float* __restrict__ W_out,
    const float* __restrict__ b_out,
    const float* __restrict__ thr_f, const float* __restrict__ thr1_f, const float* __restrict__ thu_f,
    const float* __restrict__ thr_b, const float* __restrict__ thr1_b, const float* __restrict__ thu_b,
    const float* __restrict__ xw,
    float* __restrict__ out,
    void* __restrict__ bwdws) {
  const int tid = threadIdx.x;
  const int l4  = tid & 15;
  const int dir = blockIdx.x >> 7;
  const int b   = blockIdx.x & 127;

  // xor4-within-row via row_shl:4 / row_shr:4 + probe-derived select (convention-proof).
  const int pshl = dpp_i<0x104>(tid);
  const int sel4 = (pshl == (tid ^ 4)) ? ~0 : 0;
  auto xor4f = [&](float x) {
    int a = dpp_i<0x104>(__float_as_int(x));
    int c = dpp_i<0x114>(__float_as_int(x));
    return __int_as_float((a & sel4) | (c & ~sel4));
  };

  // row_ror direction probe: ror:1 on the row-lane index. Wave-uniform bool.
  const int q1 = dpp_i<0x121>(l4);
  const bool dplus = (q1 == ((l4 + 1) & 15));   // true: ror:c reads lane (l+c)&15

  // +/- butterfly: eb[B](l) = (-1)^{l_B} * sum_s p[s]*(1-2*bit_B(s)); n2 = sum p.
  auto ebf = [&](float p, float& n2, float* eb) {
    float s4 = xor4f(p);
    float P  = p + s4, M2 = p - s4;
    float dP = dpp_f<0x128>(P), dM2 = dpp_f<0x128>(M2);
    float P3 = P + dP, M3 = P - dP; M2 = M2 + dM2;
    float a1 = dpp_f<0x4E>(P3), a2 = dpp_f<0x4E>(M3), a3 = dpp_f<0x4E>(M2);
    float P1 = P3 + a1, M1 = P3 - a1; M3 += a2; M2 += a3;
    float b0_ = dpp_f<0xB1>(P1), b1_ = dpp_f<0xB1>(M1), b3_ = dpp_f<0xB1>(M3), b2_ = dpp_f<0xB1>(M2);
    n2 = P1 + b0_;
    eb[0] = P1 - b0_; eb[1] = M1 + b1_; eb[3] = M3 + b3_; eb[2] = M2 + b2_;
  };

  // ---- per-lane constants ----
  const float* thr  = dir ? thr_b  : thr_f;
  const float* thr1 = dir ? thr1_b : thr1_f;
  const float* thu  = dir ? thu_b  : thu_f;

  const int k0 = 2 * tid, k1 = 2 * tid + 1;   // this lane's hidden units (k == m)

  // W_h, ROTATION layout + CNOT perm folded: slot i holds column g((i + l4) & 15).
  f32x2 w0p[8], w1p[8];
#pragma unroll
  for (int i = 0; i < 8; ++i) {
    int ja = gperm((2 * i + l4) & 15), jb = gperm((2 * i + 1 + l4) & 15);
    f32x2 a, c;
    a.x = W_in[k0 * QDIM + ja];  a.y = W_in[k0 * QDIM + jb];
    c.x = W_in[k1 * QDIM + ja];  c.y = W_in[k1 * QDIM + jb];
    w0p[i] = a; w1p[i] = c;
  }

  // W_out pk pairs over (m = k0, k1), wire w = 3-B, with e-butterfly sign
  // (-1)^{l_B}, the analytic cos(theta_w) factor, AND the log2(e) gate-scale
  // folded in (woR/woZ: -L2E for sigmoid; woH: +2*L2E for tanh).
  const float L2E = 1.4426950408889634f;
  f32x2 woRpk[4], woZpk[4], woHpk[4];
#pragma unroll
  for (int B = 0; B < 4; ++B) {
    float sgn = ((tid >> B) & 1) ? -1.f : 1.f;
    float cR = cosf(thr[3 - B])  * sgn * (-L2E);
    float cZ = cosf(thu[3 - B])  * sgn * (-L2E);
    float cH = cosf(thr1[3 - B]) * sgn * (2.f * L2E);
    float wo0 = W_out[(3 - B) * HID + k0];
    float wo1 = W_out[(3 - B) * HID + k1];
    f32x2 rr_, zz_, hh_;
    rr_.x = wo0 * cR;  rr_.y = wo1 * cR;
    zz_.x = wo0 * cZ;  zz_.y = wo1 * cZ;
    hh_.x = wo0 * cH;  hh_.y = wo1 * cH;
    woRpk[B] = rr_; woZpk[B] = zz_; woHpk[B] = hh_;
  }
  f32x2 nbcpk, bc2pk;
  nbcpk.x = -b_out[k0] * L2E;         nbcpk.y = -b_out[k1] * L2E;
  bc2pk.x =  b_out[k0] * (2.f * L2E); bc2pk.y =  b_out[k1] * (2.f * L2E);

  // tree dot: 3 dependency levels
  auto dot4pk = [](const float* e, const f32x2* w) -> f32x2 {
    f32x2 d01 = s2(e[1]) * w[1] + s2(e[0]) * w[0];
    f32x2 d23 = s2(e[3]) * w[3] + s2(e[2]) * w[2];
    return d01 + d23;
  };

  auto body = [&](auto dpc) {
    constexpr bool DP = decltype(dpc)::value;
    constexpr int C2 = DP ? 0x12C : 0x124;   // ror:12 / ror:4
    constexpr int C3 = DP ? 0x12E : 0x122;   // ror:14 / ror:2
    constexpr int C4 = DP ? 0x12F : 0x121;   // ror:15 / ror:1

    // rotation-layout reduce-scatter: v[i] = partial of column (l4+i)&15.
    // Output: full 64-lane sum for column l4, replicated in every lane.
    auto bfr = [&](const float* v) -> float {
      float w1[8];
#pragma unroll
      for (int j = 0; j < 8; ++j) w1[j] = v[j] + dpp_f<0x128>(v[j + 8]);
      float w2[4];
#pragma unroll
      for (int j = 0; j < 4; ++j) w2[j] = w1[j] + dpp_f<C2>(w1[j + 4]);
      float w3[2];
#pragma unroll
      for (int j = 0; j < 2; ++j) w3[j] = w2[j] + dpp_f<C3>(w2[j + 2]);
      float y0 = w3[0] + dpp_f<C4>(w3[1]);
      return pls32_sum(pls16_sum(y0));
    };

    f32x2 hpk; hpk.x = 0.f; hpk.y = 0.f;   // h[k0], h[k1]
    const float* pxw = xw + ((long)b * TSEQ + (dir ? TSEQ - 1 : 0)) * QDIM;
    const long xstep = dir ? -QDIM : QDIM;
    float xc = pxw[l4]; pxw += xstep;
    float xn = pxw[l4]; pxw += xstep;

    float* po  = out + (long)b * TSEQ * HID + k0;
    u32*   pbh = (u32*)bwdws + ((long)b * TSEQ * HID >> 1) + tid;

#pragma unroll 1
    for (int t = 0; t < TSEQ; ++t) {
      float xnn = pxw[l4]; pxw += xstep;   // prefetch t+2 (ws padded; overrun harmless)

      // ---- y = h @ W_h (rotated cols) + xwP ----
      f32x2 hh0 = s2(hpk.x);
      f32x2 hh1 = s2(hpk.y);
      float v[16];
#pragma unroll
      for (int i = 0; i < 8; ++i) {
        f32x2 a = hh0 * w0p[i] + hh1 * w1p[i];
        v[2 * i] = a.x; v[2 * i + 1] = a.y;
      }
      float yv = bfr(v) + xc;

      // ---- VQC1 collapsed: p[col] = yP[col]^2 ----
      float prb = yv * yv;

      float n2, eb[4];
      ebf(prb, n2, eb);
      float inv = rcpf(n2);   // n2 == |y|^2, shared by both gate types

      // gate dots (tables carry cos(theta), sign, and L2E scale)
      f32x2 rd = dot4pk(eb, woRpk);
      f32x2 zd = dot4pk(eb, woZpk);

      f32x2 ra = rd * s2(inv) + nbcpk;
      f32x2 za = zd * s2(inv) + nbcpk;
      float r0 = rcpf(1.f + ex2(ra.x));
      float r1 = rcpf(1.f + ex2(ra.y));
      float z0 = rcpf(1.f + ex2(za.x));
      float z1 = rcpf(1.f + ex2(za.y));

      // off-chain blend prep: q = z + (1-z)h ; s = -2z (ready during matvec2)
      f32x2 zpk;  zpk.x = z0; zpk.y = z1;
      f32x2 omz = s2(1.f) - zpk;
      f32x2 qpk = omz * hpk + zpk;
      f32x2 spk = s2(-2.f) * zpk;

      // ---- v1 = (r*h) @ W_h + xwP ----
      f32x2 rpk; rpk.x = r0; rpk.y = r1;
      f32x2 rh = rpk * hpk;
      hh0 = s2(rh.x);
      hh1 = s2(rh.y);
#pragma unroll
      for (int i = 0; i < 8; ++i) {
        f32x2 a = hh0 * w0p[i] + hh1 * w1p[i];
        v[2 * i] = a.x; v[2 * i + 1] = a.y;
      }
      float vv = bfr(v) + xc;

      // ---- VQC2 collapsed ----
      float prb2 = vv * vv;

      float n2b, eb2[4];
      ebf(prb2, n2b, eb2);
      float invb = rcpf(n2b);
      f32x2 hd = dot4pk(eb2, woHpk);
      f32x2 ha = hd * s2(invb) + bc2pk;
      // w = 1/(1+e^{2a}); h2 = 1-2w; hn = z*h2+(1-z)h = s*w + q
      float wq0 = rcpf(1.f + ex2(ha.x));
      float wq1 = rcpf(1.f + ex2(ha.y));
      f32x2 wpk; wpk.x = wq0; wpk.y = wq1;
      hpk = spk * wpk + qpk;

      f32x2 opk = hpk * s2(0.5f);
      if (dir == 0) {
        *reinterpret_cast<f32x2*>(po) = opk;
        po += HID;
      } else {
        *pbh = (u32)f2bf(opk.x) | ((u32)f2bf(opk.y) << 16);
        pbh += HID / 2;
      }

      xc = xn; xn = xnn;
    }
  };

  if (dplus) body(std::integral_constant<bool, true>{});
  else       body(std::integral_constant<bool, false>{});
}

// ---------------- kernel 3: out += bwd trajectory (bf16 ws) ----------------

__global__ __launch_bounds__(256) void combine_k(float* __restrict__ out,
                                                 const void* __restrict__ bwd, long n4) {
  long i = (long)blockIdx.x * 256 + threadIdx.x;
  const long stride = (long)gridDim.x * 256;
  for (; i < n4; i += stride) {
    float4 o = reinterpret_cast<float4*>(out)[i];
    ushort4 u = reinterpret_cast<const ushort4*>(bwd)[i];
    o.x += __uint_as_float((u32)u.x << 16);
    o.y += __uint_as_float((u32)u.y << 16);
    o.z += __uint_as_float((u32)u.z << 16);
    o.w += __uint_as_float((u32)u.w << 16);
    reinterpret_cast<float4*>(out)[i] = o;
  }
}

// ---------------- launch ----------------

extern "C" void kernel_launch(void* const* d_in, const int* in_sizes, int n_in,
                              void* d_out, int out_size, void* d_ws, size_t ws_size,
                              hipStream_t stream) {
  const float* x     = (const float*)d_in[0];
  const float* W_in  = (const float*)d_in[1];
  const float* b_in  = (const float*)d_in[2];
  const float* W_out = (const float*)d_in[3];
  const float* b_out = (const float*)d_in[4];
  const float* thr_f  = (const float*)d_in[5];
  const float* thr1_f = (const float*)d_in[6];
  const float* thu_f  = (const float*)d_in[7];
  const float* thr_b  = (const float*)d_in[8];
  const float* thr1_b = (const float*)d_in[9];
  const float* thu_b  = (const float*)d_in[10];
  float* out = (float*)d_out;

  char* ws = (char*)d_ws;
  const size_t PAD = 4096;   // xw prefetch over/under-run guard
  const size_t xw_bytes = (size_t)NB * TSEQ * QDIM * sizeof(float);   // 8 MB
  float* xw = (float*)(ws + PAD);
  void* bwd = (void*)(ws + PAD + xw_bytes + PAD);

  xw_kernel<<<(NB * TSEQ) / 16, 256, 0, stream>>>(x, W_in, b_in, xw);

  qbigru_main<<<256, 64, 0, stream>>>(W_in, W_out, b_out,
      thr_f, thr1_f, thu_f, thr_b, thr1_b, thu_b, xw, out, bwd);

  const long n4 = (long)NB * TSEQ * HID / 4;
  combine_k<<<2048, 256, 0, stream>>>(out, bwd, n4);
}